// Round 5
// baseline (3108.806 us; speedup 1.0000x reference)
//
#include <hip/hip_runtime.h>
#include <hip/hip_bf16.h>
#include <cstdint>

#define S_LEN 1024
#define DMODEL 1352
#define TD 4056
#define DFFN 2704
#define NHEAD 8
#define HDIM 169
#define NLAYER 7
#define LDAP 1376   // 1352 -> 43*32
#define KP2 2720    // 2704 -> 85*32
#define QS 1536     // 8 heads * 192
#define HP 192      // head dim padded to 6*32

typedef __attribute__((ext_vector_type(8))) short short8;
typedef __attribute__((ext_vector_type(4))) float f32x4;
typedef __attribute__((ext_vector_type(2))) unsigned short us2;
typedef __attribute__((ext_vector_type(4))) unsigned short us4;

__device__ __forceinline__ unsigned short f2bf(float f) {
    union { float f; unsigned int u; } c; c.f = f;
    unsigned int r = (c.u + 0x7fffu + ((c.u >> 16) & 1u)) >> 16;
    return (unsigned short)r;
}

__device__ __forceinline__ void g2l16(const void* g, void* l) {
    __builtin_amdgcn_global_load_lds((__attribute__((address_space(1))) void*)g,
                                     (__attribute__((address_space(3))) void*)l,
                                     16, 0, 0);
}

// ---------------- routing ----------------
__global__ __launch_bounds__(256) void route_k(const float* __restrict__ x,
                                               int* __restrict__ perm,
                                               int* __restrict__ pcnt) {
    const int tid = threadIdx.x;
    const int lane = tid & 63;
    const int w = tid >> 6;
    for (int i = tid; i < 4096; i += 256) perm[i] = -1;
    __syncthreads();
    int base = 0;
    for (int c = 0; c < 16; ++c) {
        const int t = c * 64 + lane;
        const float* xr = x + (long long)t * DMODEL;
        float best = xr[0]; int bi = 0;
        #pragma unroll
        for (int j = 1; j < 16; ++j) { float v = xr[j]; if (v > best) { best = v; bi = j; } }
        const bool match = ((bi & 3) == w);
        unsigned long long mb = __ballot(match);
        int pos = __popcll(mb & ((1ull << lane) - 1ull));
        if (match) perm[w * 1024 + base + pos] = t;
        base += __popcll(mb);
    }
    if (lane == 0) pcnt[w] = (base + 127) & ~127;
}

// ---------------- layernorm -> bf16 ----------------
__global__ __launch_bounds__(256) void ln_k(const float* __restrict__ h,
                                            const float* __restrict__ g,
                                            const float* __restrict__ b,
                                            unsigned short* __restrict__ out,
                                            int D, int ldo) {
    const int row = blockIdx.x;
    const float* hr = h + (long long)row * D;
    float s = 0.f, s2 = 0.f;
    for (int j = threadIdx.x; j < D; j += 256) { float v = hr[j]; s += v; s2 += v * v; }
    __shared__ float sA[4], sB[4];
    #pragma unroll
    for (int o = 32; o; o >>= 1) { s += __shfl_xor(s, o, 64); s2 += __shfl_xor(s2, o, 64); }
    const int lane = threadIdx.x & 63, wid = threadIdx.x >> 6;
    if (lane == 0) { sA[wid] = s; sB[wid] = s2; }
    __syncthreads();
    s = sA[0] + sA[1] + sA[2] + sA[3];
    s2 = sB[0] + sB[1] + sB[2] + sB[3];
    const float mu = s / D;
    const float rstd = rsqrtf(fmaxf(s2 / D - mu * mu, 0.f) + 1e-5f);
    unsigned short* orow = out + (long long)row * ldo;
    for (int j = threadIdx.x; j < ldo; j += 256) {
        float v = (j < D) ? (hr[j] - mu) * rstd * g[j] + b[j] : 0.f;
        orow[j] = f2bf(v);
    }
}

// ---------------- transpose+convert: f32 [K][N] -> bf16 [N][Kp] ----------------
__global__ __launch_bounds__(256) void tconv_k(const float* __restrict__ src,
                                               unsigned short* __restrict__ dst,
                                               int K, int N, int Kp,
                                               long long zsrc, long long zdst) {
    src += (long long)blockIdx.z * zsrc;
    dst += (long long)blockIdx.z * zdst;
    __shared__ float t[32][33];
    const int k0 = blockIdx.x * 32, n0 = blockIdx.y * 32;
    const int tx = threadIdx.x & 31, ty = threadIdx.x >> 5;
    #pragma unroll
    for (int i = 0; i < 4; ++i) {
        int k = k0 + ty + i * 8, n = n0 + tx;
        t[ty + i * 8][tx] = (k < K && n < N) ? src[(long long)k * N + n] : 0.f;
    }
    __syncthreads();
    #pragma unroll
    for (int i = 0; i < 2; ++i) {
        int s = threadIdx.x + i * 256;
        int nr = s >> 4;
        int kp = (s & 15) * 2;
        int n = n0 + nr;
        if (n < N) {
            us2 w; w.x = f2bf(t[kp][nr]); w.y = f2bf(t[kp + 1][nr]);
            *(us2*)&dst[(long long)n * Kp + k0 + kp] = w;
        }
    }
}

// ---------------- fused flash attention ----------------
// grid (8 qtiles, 8 heads), 256 thr; wave w owns 32 q-rows. No barriers:
// waves fully independent (per-wave LDS regions, wave-synchronous reuse).
__global__ __launch_bounds__(256) void flash_k(
    const unsigned short* __restrict__ qb,
    const unsigned short* __restrict__ kb,
    const unsigned short* __restrict__ VT,
    unsigned short* __restrict__ obuf,
    float scale) {
    const int h = blockIdx.y;
    const int tid = threadIdx.x, lane = tid & 63, w = tid >> 6;
    const int q0 = blockIdx.x * 128 + w * 32;
    const int l15 = lane & 15, lg = lane >> 4;

    __shared__ unsigned short P_lds[4][32][40];   // [wave][q][k], stride 40 (2-way max)
    __shared__ float stat[4][32];                 // per-wave q-indexed bounce buffer

    // Q fragments (B-operand): q = q0 + qf*16 + l15, d-chunk c
    short8 qfr[2][6];
    #pragma unroll
    for (int qf = 0; qf < 2; ++qf)
        #pragma unroll
        for (int c = 0; c < 6; ++c)
            qfr[qf][c] = *(const short8*)&qb[(long long)(q0 + qf * 16 + l15) * QS + h * HP + c * 32 + lg * 8];

    f32x4 acc[2][11] = {};
    float m_run[2] = {-1e30f, -1e30f};
    float l_run[2] = {0.f, 0.f};

    const int nt = q0 / 32 + 1;
    for (int kt = 0; kt < nt; ++kt) {
        // S^T[k][q] = K @ Q^T
        f32x4 st[2][2] = {};   // [kf][qf]
        #pragma unroll
        for (int kf = 0; kf < 2; ++kf)
            #pragma unroll
            for (int c = 0; c < 6; ++c) {
                short8 a = *(const short8*)&kb[(long long)(kt * 32 + kf * 16 + l15) * QS + h * HP + c * 32 + lg * 8];
                #pragma unroll
                for (int qf = 0; qf < 2; ++qf)
                    st[kf][qf] = __builtin_amdgcn_mfma_f32_16x16x32_bf16(a, qfr[qf][c], st[kf][qf], 0, 0, 0);
            }
        // scale + causal mask on diagonal tile
        const bool diag = (kt == nt - 1);
        #pragma unroll
        for (int kf = 0; kf < 2; ++kf)
            #pragma unroll
            for (int qf = 0; qf < 2; ++qf)
                #pragma unroll
                for (int r = 0; r < 4; ++r) {
                    float s = st[kf][qf][r] * scale;
                    if (diag) {
                        const int kA = kt * 32 + kf * 16 + lg * 4 + r;
                        const int qA = q0 + qf * 16 + l15;
                        if (kA > qA) s = -1e30f;
                    }
                    st[kf][qf][r] = s;
                }
        // online softmax per q (column of S^T; q = l15 domain)
        #pragma unroll
        for (int qf = 0; qf < 2; ++qf) {
            float tmax = -1e30f;
            #pragma unroll
            for (int kf = 0; kf < 2; ++kf)
                #pragma unroll
                for (int r = 0; r < 4; ++r) tmax = fmaxf(tmax, st[kf][qf][r]);
            tmax = fmaxf(tmax, __shfl_xor(tmax, 16, 64));
            tmax = fmaxf(tmax, __shfl_xor(tmax, 32, 64));
            const float mn = fmaxf(m_run[qf], tmax);
            const float esc = __expf(m_run[qf] - mn);
            float tsum = 0.f;
            #pragma unroll
            for (int kf = 0; kf < 2; ++kf)
                #pragma unroll
                for (int r = 0; r < 4; ++r) {
                    float p = __expf(st[kf][qf][r] - mn);
                    st[kf][qf][r] = p; tsum += p;
                }
            tsum += __shfl_xor(tsum, 16, 64);
            tsum += __shfl_xor(tsum, 32, 64);
            l_run[qf] = l_run[qf] * esc + tsum;
            m_run[qf] = mn;
            if (lane < 16) stat[w][qf * 16 + lane] = esc;
        }
        // write P^T -> P_lds[q][k] (bf16, 4 contiguous k per write)
        #pragma unroll
        for (int qf = 0; qf < 2; ++qf)
            #pragma unroll
            for (int kf = 0; kf < 2; ++kf) {
                us4 pk;
                #pragma unroll
                for (int r = 0; r < 4; ++r) pk[r] = f2bf(st[kf][qf][r]);
                *(us4*)&P_lds[w][qf * 16 + l15][kf * 16 + lg * 4] = pk;
            }
        // rescale acc (row domain: q = lg*4 + r)
        f32x4 e0 = *(f32x4*)&stat[w][lg * 4];
        f32x4 e1 = *(f32x4*)&stat[w][16 + lg * 4];
        #pragma unroll
        for (int qf = 0; qf < 2; ++qf) {
            f32x4 e = qf ? e1 : e0;
            #pragma unroll
            for (int d = 0; d < 11; ++d)
                #pragma unroll
                for (int r = 0; r < 4; ++r) acc[qf][d][r] *= e[r];
        }
        // PV: A = P (m=q), B = V (n=d)
        short8 pa0 = *(const short8*)&P_lds[w][l15][lg * 8];
        short8 pa1 = *(const short8*)&P_lds[w][16 + l15][lg * 8];
        #pragma unroll
        for (int d = 0; d < 11; ++d) {
            short8 vb = *(const short8*)&VT[(long long)(h * 256 + d * 16 + l15) * 1024 + kt * 32 + lg * 8];
            acc[0][d] = __builtin_amdgcn_mfma_f32_16x16x32_bf16(pa0, vb, acc[0][d], 0, 0, 0);
            acc[1][d] = __builtin_amdgcn_mfma_f32_16x16x32_bf16(pa1, vb, acc[1][d], 0, 0, 0);
        }
    }

    // epilogue: O = acc / l, write compact cols h*169 + d (d<169)
    if (lane < 16) { stat[w][lane] = l_run[0]; stat[w][16 + lane] = l_run[1]; }
    f32x4 L0 = *(f32x4*)&stat[w][lg * 4];
    f32x4 L1 = *(f32x4*)&stat[w][16 + lg * 4];
    #pragma unroll
    for (int qf = 0; qf < 2; ++qf) {
        f32x4 L = qf ? L1 : L0;
        #pragma unroll
        for (int d = 0; d < 11; ++d) {
            const int dd = d * 16 + l15;
            if (dd >= HDIM) continue;
            #pragma unroll
            for (int r = 0; r < 4; ++r) {
                const int q = q0 + qf * 16 + lg * 4 + r;
                obuf[(long long)q * LDAP + h * HDIM + dd] = f2bf(acc[qf][d][r] / L[r]);
            }
        }
    }
}

// ---------------- pipelined bf16 MFMA GEMM, 128x128x32, 3-buffer counted vmcnt ----
template<int EPI, bool GATHER, int CAUSAL>
__global__ __launch_bounds__(256) void gemm2_k(
    const unsigned short* __restrict__ A_, int lda, long long zsA,
    const unsigned short* __restrict__ B_, int ldb, long long zsB,
    void* __restrict__ C_, int ldc, long long zsC,
    const float* __restrict__ bias_, long long zsBias,
    const int* __restrict__ perm_, const int* __restrict__ pcnt,
    int N, int Kp,
    unsigned short* __restrict__ q_, unsigned short* __restrict__ k_,
    unsigned short* __restrict__ vt_) {
    const int z = blockIdx.z;
    const int gm0 = blockIdx.y * 128;
    const int n0 = blockIdx.x * 128;
    if (pcnt && gm0 >= pcnt[z]) return;
    if (CAUSAL == 1 && n0 >= gm0 + 128) return;

    const unsigned short* A = A_ + (long long)z * zsA;
    const unsigned short* B = B_ + (long long)z * zsB;
    const float* bias = bias_ ? bias_ + (long long)z * zsBias : nullptr;
    const int* perm = perm_ ? perm_ + (long long)z * 1024 : nullptr;

    __shared__ unsigned short Al[3][128 * 32];
    __shared__ unsigned short Bl[3][128 * 32];

    const int tid = threadIdx.x, lane = tid & 63, wid = tid >> 6;
    const int wr = wid >> 1, wc = wid & 1;
    const int c0 = wid * 2;
    const int lrow = lane >> 2;
    const int lseg = (lane & 3) * 8;

    const unsigned short* gA[2];
    const unsigned short* gB[2];
    #pragma unroll
    for (int i = 0; i < 2; ++i) {
        const int row = (c0 + i) * 16 + lrow;
        int ar = gm0 + row;
        if (GATHER) { const int p = perm[ar]; ar = (p < 0) ? 0 : p; }
        gA[i] = A + (long long)ar * lda + lseg;
        gB[i] = B + (long long)(n0 + row) * ldb + lseg;
    }

    int nt = Kp >> 5;
    if (CAUSAL == 2) { int ke = gm0 + 128; if (ke > Kp) ke = Kp; nt = ke >> 5; }

    f32x4 acc[4][4] = {};

    {
        const int t1 = (nt > 1) ? 1 : 0;
        #pragma unroll
        for (int i = 0; i < 2; ++i) {
            g2l16(gA[i], &Al[0][(c0 + i) * 512]);
            g2l16(gB[i], &Bl[0][(c0 + i) * 512]);
        }
        #pragma unroll
        for (int i = 0; i < 2; ++i) {
            g2l16(gA[i] + t1 * 32, &Al[1][(c0 + i) * 512]);
            g2l16(gB[i] + t1 * 32, &Bl[1][(c0 + i) * 512]);
        }
    }

    for (int t = 0; t < nt; ++t) {
        asm volatile("s_waitcnt vmcnt(4)" ::: "memory");
        __builtin_amdgcn_s_barrier();
        __builtin_amdgcn_sched_barrier(0);
        {
            const int ts = (t + 2 < nt) ? t + 2 : nt - 1;
            const int ko = ts * 32;
            const int bi = (t + 2) % 3;
            #pragma unroll
            for (int i = 0; i < 2; ++i) {
                g2l16(gA[i] + ko, &Al[bi][(c0 + i) * 512]);
                g2l16(gB[i] + ko, &Bl[bi][(c0 + i) * 512]);
            }
        }
        const int cur = t % 3;
        const int l15 = lane & 15, kfr = (lane >> 4) * 8;
        short8 af[4], bfv[4];
        #pragma unroll
        for (int m = 0; m < 4; ++m)
            af[m] = *(const short8*)&Al[cur][(wr * 64 + m * 16 + l15) * 32 + kfr];
        #pragma unroll
        for (int n = 0; n < 4; ++n)
            bfv[n] = *(const short8*)&Bl[cur][(wc * 64 + n * 16 + l15) * 32 + kfr];
        #pragma unroll
        for (int m = 0; m < 4; ++m)
            #pragma unroll
            for (int n = 0; n < 4; ++n)
                acc[m][n] = __builtin_amdgcn_mfma_f32_16x16x32_bf16(af[m], bfv[n], acc[m][n], 0, 0, 0);
    }

    // DRAIN: no LDS-DMA may be in flight at s_endpgm (round-3 race)
    asm volatile("s_waitcnt vmcnt(0) lgkmcnt(0)" ::: "memory");

    const int l15 = lane & 15, lq = (lane >> 4) * 4;
    #pragma unroll
    for (int m = 0; m < 4; ++m) {
        const int trow = wr * 64 + m * 16 + lq;
        #pragma unroll
        for (int n = 0; n < 4; ++n) {
            const int col = n0 + wc * 64 + n * 16 + l15;
            if (col >= N) continue;
            const float bv = bias ? bias[col] : 0.f;
            if (EPI == 5) {
                const int role = col / 1352;
                const int within = col - role * 1352;
                const int hh = within / 169;
                const int dd = within - hh * 169;
                if (role == 2) {
                    us4 pk;
                    #pragma unroll
                    for (int r = 0; r < 4; ++r) pk[r] = f2bf(acc[m][n][r] + bv);
                    *(us4*)&vt_[(long long)(hh * 256 + dd) * 1024 + gm0 + trow] = pk;
                } else {
                    unsigned short* dstb = role ? k_ : q_;
                    #pragma unroll
                    for (int r = 0; r < 4; ++r)
                        dstb[(long long)(gm0 + trow + r) * QS + hh * HP + dd] =
                            f2bf(acc[m][n][r] + bv);
                }
            } else {
                #pragma unroll
                for (int r = 0; r < 4; ++r) {
                    const int grow = gm0 + trow + r;
                    const float v = acc[m][n][r] + bv;
                    if (EPI == 0) {
                        ((float*)C_)[(long long)z * zsC + (long long)grow * ldc + col] = v;
                    } else if (EPI == 1) {
                        const int tok = perm[grow];
                        ((unsigned short*)C_)[(long long)z * zsC + (long long)grow * ldc + col] =
                            (tok >= 0) ? f2bf(fmaxf(v, 0.f)) : (unsigned short)0;
                    } else if (EPI == 2) {
                        ((float*)C_)[(long long)grow * ldc + col] += v;
                    } else if (EPI == 3) {
                        const int tok = perm[grow];
                        if (tok >= 0) ((float*)C_)[(long long)tok * ldc + col] += v;
                    }
                }
            }
        }
    }
}

extern "C" void kernel_launch(void* const* d_in, const int* in_sizes, int n_in,
                              void* d_out, int out_size, void* d_ws, size_t ws_size,
                              hipStream_t stream) {
    const float* x     = (const float*)d_in[0];
    const float* ln1_g = (const float*)d_in[1];
    const float* ln1_b = (const float*)d_in[2];
    const float* wqkv  = (const float*)d_in[3];
    const float* bqkv  = (const float*)d_in[4];
    const float* wo    = (const float*)d_in[5];
    const float* bo    = (const float*)d_in[6];
    const float* ln2_g = (const float*)d_in[7];
    const float* ln2_b = (const float*)d_in[8];
    const float* w1    = (const float*)d_in[9];
    const float* b1    = (const float*)d_in[10];
    const float* w2    = (const float*)d_in[11];
    const float* b2    = (const float*)d_in[12];

    float* h = (float*)d_out;

    char* w = (char*)d_ws;
    auto alloc = [&](size_t bytes) { void* p = w; w += (bytes + 255) & ~255ull; return p; };
    unsigned short* lnA   = (unsigned short*)alloc((size_t)S_LEN * LDAP * 2);
    unsigned short* qb    = (unsigned short*)alloc((size_t)S_LEN * QS * 2);
    unsigned short* kb    = (unsigned short*)alloc((size_t)S_LEN * QS * 2);
    unsigned short* VT    = (unsigned short*)alloc((size_t)NHEAD * 256 * 1024 * 2);
    unsigned short* obufb = (unsigned short*)alloc((size_t)S_LEN * LDAP * 2);
    unsigned short* hid   = (unsigned short*)alloc((size_t)4096 * KP2 * 2);
    unsigned short* wqkvT = (unsigned short*)alloc((size_t)NLAYER * 4096 * LDAP * 2);   // 79 MB
    unsigned short* woT   = (unsigned short*)alloc((size_t)NLAYER * 1408 * LDAP * 2);   // 27 MB
    unsigned short* w1T   = (unsigned short*)alloc((size_t)NLAYER * 4 * 2816 * LDAP * 2); // 217 MB
    unsigned short* w2T   = (unsigned short*)alloc((size_t)NLAYER * 4 * 1408 * KP2 * 2);  // 214 MB
    int* perm = (int*)alloc(4096 * 4);
    int* pcnt = (int*)alloc(64);

    hipMemcpyAsync(h, x, (size_t)S_LEN * DMODEL * 4, hipMemcpyDeviceToDevice, stream);
    // q/k head-pad slots enter the QK^T MFMA -> must be zero
    hipMemsetAsync(qb, 0, (size_t)S_LEN * QS * 2, stream);
    hipMemsetAsync(kb, 0, (size_t)S_LEN * QS * 2, stream);
    route_k<<<1, 256, 0, stream>>>(x, perm, pcnt);

    // ---- all-layer weight transpose+convert (4 dispatches, fully parallel) ----
    tconv_k<<<dim3(43, 127, NLAYER), 256, 0, stream>>>(
        wqkv, wqkvT, DMODEL, TD, LDAP, (long long)DMODEL * TD, (long long)4096 * LDAP);
    tconv_k<<<dim3(43, 43, NLAYER), 256, 0, stream>>>(
        wo, woT, DMODEL, DMODEL, LDAP, (long long)DMODEL * DMODEL, (long long)1408 * LDAP);
    tconv_k<<<dim3(43, 85, NLAYER * 4), 256, 0, stream>>>(
        w1, w1T, DMODEL, DFFN, LDAP, (long long)DMODEL * DFFN, (long long)2816 * LDAP);
    tconv_k<<<dim3(85, 43, NLAYER * 4), 256, 0, stream>>>(
        w2, w2T, DFFN, DMODEL, KP2, (long long)DFFN * DMODEL, (long long)1408 * KP2);

    const float scale = 1.0f / 13.0f;

    for (int l = 0; l < NLAYER; ++l) {
        const unsigned short* wqkvT_l = wqkvT + (size_t)l * 4096 * LDAP;
        const unsigned short* woT_l   = woT   + (size_t)l * 1408 * LDAP;
        const unsigned short* w1T_l   = w1T   + (size_t)l * 4 * 2816 * LDAP;
        const unsigned short* w2T_l   = w2T   + (size_t)l * 4 * 1408 * KP2;

        ln_k<<<1024, 256, 0, stream>>>(h, ln1_g + l * DMODEL, ln1_b + l * DMODEL, lnA, DMODEL, LDAP);
        // QKV -> split bf16 q/k (head-padded) + V transposed
        gemm2_k<5, false, 0><<<dim3(32, 8, 1), 256, 0, stream>>>(
            lnA, LDAP, 0, wqkvT_l, LDAP, 0, nullptr, 0, 0,
            bqkv + l * TD, 0, nullptr, nullptr, TD, LDAP, qb, kb, VT);
        // fused flash attention -> obufb [1024][1376] (compact cols, bf16)
        flash_k<<<dim3(8, 8), 256, 0, stream>>>(qb, kb, VT, obufb, scale);
        // h += o @ wo + bo
        gemm2_k<2, false, 0><<<dim3(11, 8, 1), 256, 0, stream>>>(
            obufb, LDAP, 0, woT_l, LDAP, 0, h, DMODEL, 0,
            bo + l * DMODEL, 0, nullptr, nullptr, DMODEL, LDAP, nullptr, nullptr, nullptr);

        ln_k<<<1024, 256, 0, stream>>>(h, ln2_g + l * DMODEL, ln2_b + l * DMODEL, lnA, DMODEL, LDAP);
        gemm2_k<1, true, 0><<<dim3(22, 8, 4), 256, 0, stream>>>(
            lnA, LDAP, 0, w1T_l, LDAP, (long long)2816 * LDAP,
            hid, KP2, (long long)1024 * KP2,
            b1 + (long long)l * 4 * DFFN, DFFN, perm, pcnt, DFFN, LDAP,
            nullptr, nullptr, nullptr);
        gemm2_k<3, false, 0><<<dim3(11, 8, 4), 256, 0, stream>>>(
            hid, KP2, (long long)1024 * KP2, w2T_l, KP2, (long long)1408 * KP2,
            h, DMODEL, 0,
            b2 + (long long)l * 4 * DMODEL, DMODEL, perm, pcnt, DMODEL, KP2,
            nullptr, nullptr, nullptr);
    }
}

// Round 6
// 2959.919 us; speedup vs baseline: 1.0503x; 1.0503x over previous
//
#include <hip/hip_runtime.h>
#include <hip/hip_bf16.h>
#include <cstdint>

#define S_LEN 1024
#define DMODEL 1352
#define TD 4056
#define DFFN 2704
#define NHEAD 8
#define HDIM 169
#define NLAYER 7
#define LDAP 1376   // 1352 -> 43*32
#define KP2 2720    // 2704 -> 85*32
#define QS 1536     // 8 heads * 192
#define HP 192      // head dim padded to 6*32

typedef __attribute__((ext_vector_type(8))) short short8;
typedef __attribute__((ext_vector_type(4))) float f32x4;
typedef __attribute__((ext_vector_type(2))) unsigned short us2;
typedef __attribute__((ext_vector_type(4))) unsigned short us4;

__device__ __forceinline__ unsigned short f2bf(float f) {
    union { float f; unsigned int u; } c; c.f = f;
    unsigned int r = (c.u + 0x7fffu + ((c.u >> 16) & 1u)) >> 16;
    return (unsigned short)r;
}

__device__ __forceinline__ void g2l16(const void* g, void* l) {
    __builtin_amdgcn_global_load_lds((__attribute__((address_space(1))) void*)g,
                                     (__attribute__((address_space(3))) void*)l,
                                     16, 0, 0);
}

// ---------------- routing ----------------
__global__ __launch_bounds__(256) void route_k(const float* __restrict__ x,
                                               int* __restrict__ perm,
                                               int* __restrict__ pcnt) {
    const int tid = threadIdx.x;
    const int lane = tid & 63;
    const int w = tid >> 6;
    for (int i = tid; i < 4096; i += 256) perm[i] = -1;
    __syncthreads();
    int base = 0;
    for (int c = 0; c < 16; ++c) {
        const int t = c * 64 + lane;
        const float* xr = x + (long long)t * DMODEL;
        float best = xr[0]; int bi = 0;
        #pragma unroll
        for (int j = 1; j < 16; ++j) { float v = xr[j]; if (v > best) { best = v; bi = j; } }
        const bool match = ((bi & 3) == w);
        unsigned long long mb = __ballot(match);
        int pos = __popcll(mb & ((1ull << lane) - 1ull));
        if (match) perm[w * 1024 + base + pos] = t;
        base += __popcll(mb);
    }
    if (lane == 0) pcnt[w] = (base + 127) & ~127;
}

// ---------------- layernorm -> bf16 ----------------
__global__ __launch_bounds__(256) void ln_k(const float* __restrict__ h,
                                            const float* __restrict__ g,
                                            const float* __restrict__ b,
                                            unsigned short* __restrict__ out,
                                            int D, int ldo) {
    const int row = blockIdx.x;
    const float* hr = h + (long long)row * D;
    float s = 0.f, s2 = 0.f;
    for (int j = threadIdx.x; j < D; j += 256) { float v = hr[j]; s += v; s2 += v * v; }
    __shared__ float sA[4], sB[4];
    #pragma unroll
    for (int o = 32; o; o >>= 1) { s += __shfl_xor(s, o, 64); s2 += __shfl_xor(s2, o, 64); }
    const int lane = threadIdx.x & 63, wid = threadIdx.x >> 6;
    if (lane == 0) { sA[wid] = s; sB[wid] = s2; }
    __syncthreads();
    s = sA[0] + sA[1] + sA[2] + sA[3];
    s2 = sB[0] + sB[1] + sB[2] + sB[3];
    const float mu = s / D;
    const float rstd = rsqrtf(fmaxf(s2 / D - mu * mu, 0.f) + 1e-5f);
    unsigned short* orow = out + (long long)row * ldo;
    for (int j = threadIdx.x; j < ldo; j += 256) {
        float v = (j < D) ? (hr[j] - mu) * rstd * g[j] + b[j] : 0.f;
        orow[j] = f2bf(v);
    }
}

// ---------------- transpose+convert: f32 [K][N] -> bf16 [N][Kp] ----------------
__global__ __launch_bounds__(256) void tconv_k(const float* __restrict__ src,
                                               unsigned short* __restrict__ dst,
                                               int K, int N, int Kp,
                                               long long zsrc, long long zdst) {
    src += (long long)blockIdx.z * zsrc;
    dst += (long long)blockIdx.z * zdst;
    __shared__ float t[32][33];
    const int k0 = blockIdx.x * 32, n0 = blockIdx.y * 32;
    const int tx = threadIdx.x & 31, ty = threadIdx.x >> 5;
    #pragma unroll
    for (int i = 0; i < 4; ++i) {
        int k = k0 + ty + i * 8, n = n0 + tx;
        t[ty + i * 8][tx] = (k < K && n < N) ? src[(long long)k * N + n] : 0.f;
    }
    __syncthreads();
    #pragma unroll
    for (int i = 0; i < 2; ++i) {
        int s = threadIdx.x + i * 256;
        int nr = s >> 4;
        int kp = (s & 15) * 2;
        int n = n0 + nr;
        if (n < N) {
            us2 w; w.x = f2bf(t[kp][nr]); w.y = f2bf(t[kp + 1][nr]);
            *(us2*)&dst[(long long)n * Kp + k0 + kp] = w;
        }
    }
}

// ---------------- fused flash attention ----------------
// grid (8 qtiles, 8 heads), 256 thr; wave w owns 32 q-rows. No barriers:
// waves fully independent (per-wave LDS regions, wave-synchronous reuse).
__global__ __launch_bounds__(256) void flash_k(
    const unsigned short* __restrict__ qb,
    const unsigned short* __restrict__ kb,
    const unsigned short* __restrict__ VT,
    unsigned short* __restrict__ obuf,
    float scale) {
    const int h = blockIdx.y;
    const int tid = threadIdx.x, lane = tid & 63, w = tid >> 6;
    const int q0 = blockIdx.x * 128 + w * 32;
    const int l15 = lane & 15, lg = lane >> 4;

    __shared__ unsigned short P_lds[4][32][40];   // [wave][q][k], stride 40
    __shared__ float stat[4][32];                 // per-wave q-indexed bounce buffer

    // Q fragments (B-operand): q = q0 + qf*16 + l15, d-chunk c
    short8 qfr[2][6];
    #pragma unroll
    for (int qf = 0; qf < 2; ++qf)
        #pragma unroll
        for (int c = 0; c < 6; ++c)
            qfr[qf][c] = *(const short8*)&qb[(long long)(q0 + qf * 16 + l15) * QS + h * HP + c * 32 + lg * 8];

    f32x4 acc[2][11] = {};
    float m_run[2] = {-1e30f, -1e30f};
    float l_run[2] = {0.f, 0.f};

    const int nt = q0 / 32 + 1;
    for (int kt = 0; kt < nt; ++kt) {
        // S^T[k][q] = K @ Q^T
        f32x4 st[2][2] = {};   // [kf][qf]
        #pragma unroll
        for (int kf = 0; kf < 2; ++kf)
            #pragma unroll
            for (int c = 0; c < 6; ++c) {
                short8 a = *(const short8*)&kb[(long long)(kt * 32 + kf * 16 + l15) * QS + h * HP + c * 32 + lg * 8];
                #pragma unroll
                for (int qf = 0; qf < 2; ++qf)
                    st[kf][qf] = __builtin_amdgcn_mfma_f32_16x16x32_bf16(a, qfr[qf][c], st[kf][qf], 0, 0, 0);
            }
        // scale + causal mask on diagonal tile
        const bool diag = (kt == nt - 1);
        #pragma unroll
        for (int kf = 0; kf < 2; ++kf)
            #pragma unroll
            for (int qf = 0; qf < 2; ++qf)
                #pragma unroll
                for (int r = 0; r < 4; ++r) {
                    float s = st[kf][qf][r] * scale;
                    if (diag) {
                        const int kA = kt * 32 + kf * 16 + lg * 4 + r;
                        const int qA = q0 + qf * 16 + l15;
                        if (kA > qA) s = -1e30f;
                    }
                    st[kf][qf][r] = s;
                }
        // online softmax per q (column of S^T; q = l15 domain)
        #pragma unroll
        for (int qf = 0; qf < 2; ++qf) {
            float tmax = -1e30f;
            #pragma unroll
            for (int kf = 0; kf < 2; ++kf)
                #pragma unroll
                for (int r = 0; r < 4; ++r) tmax = fmaxf(tmax, st[kf][qf][r]);
            tmax = fmaxf(tmax, __shfl_xor(tmax, 16, 64));
            tmax = fmaxf(tmax, __shfl_xor(tmax, 32, 64));
            const float mn = fmaxf(m_run[qf], tmax);
            const float esc = __expf(m_run[qf] - mn);
            float tsum = 0.f;
            #pragma unroll
            for (int kf = 0; kf < 2; ++kf)
                #pragma unroll
                for (int r = 0; r < 4; ++r) {
                    float p = __expf(st[kf][qf][r] - mn);
                    st[kf][qf][r] = p; tsum += p;
                }
            tsum += __shfl_xor(tsum, 16, 64);
            tsum += __shfl_xor(tsum, 32, 64);
            l_run[qf] = l_run[qf] * esc + tsum;
            m_run[qf] = mn;
            if (lane < 16) stat[w][qf * 16 + lane] = esc;
        }
        // write P^T -> P_lds[q][k] (bf16, 4 contiguous k per write)
        #pragma unroll
        for (int qf = 0; qf < 2; ++qf)
            #pragma unroll
            for (int kf = 0; kf < 2; ++kf) {
                us4 pk;
                #pragma unroll
                for (int r = 0; r < 4; ++r) pk[r] = f2bf(st[kf][qf][r]);
                *(us4*)&P_lds[w][qf * 16 + l15][kf * 16 + lg * 4] = pk;
            }
        // rescale acc (row domain: q = lg*4 + r)
        f32x4 e0 = *(f32x4*)&stat[w][lg * 4];
        f32x4 e1 = *(f32x4*)&stat[w][16 + lg * 4];
        #pragma unroll
        for (int qf = 0; qf < 2; ++qf) {
            f32x4 e = qf ? e1 : e0;
            #pragma unroll
            for (int d = 0; d < 11; ++d)
                #pragma unroll
                for (int r = 0; r < 4; ++r) acc[qf][d][r] *= e[r];
        }
        // PV: A = P (m=q), B = V (n=d)
        short8 pa0 = *(const short8*)&P_lds[w][l15][lg * 8];
        short8 pa1 = *(const short8*)&P_lds[w][16 + l15][lg * 8];
        #pragma unroll
        for (int d = 0; d < 11; ++d) {
            short8 vb = *(const short8*)&VT[(long long)(h * 256 + d * 16 + l15) * 1024 + kt * 32 + lg * 8];
            acc[0][d] = __builtin_amdgcn_mfma_f32_16x16x32_bf16(pa0, vb, acc[0][d], 0, 0, 0);
            acc[1][d] = __builtin_amdgcn_mfma_f32_16x16x32_bf16(pa1, vb, acc[1][d], 0, 0, 0);
        }
    }

    // epilogue: O = acc / l, write compact cols h*169 + d (d<169)
    if (lane < 16) { stat[w][lane] = l_run[0]; stat[w][16 + lane] = l_run[1]; }
    f32x4 L0 = *(f32x4*)&stat[w][lg * 4];
    f32x4 L1 = *(f32x4*)&stat[w][16 + lg * 4];
    #pragma unroll
    for (int qf = 0; qf < 2; ++qf) {
        f32x4 L = qf ? L1 : L0;
        #pragma unroll
        for (int d = 0; d < 11; ++d) {
            const int dd = d * 16 + l15;
            if (dd >= HDIM) continue;
            #pragma unroll
            for (int r = 0; r < 4; ++r) {
                const int q = q0 + qf * 16 + lg * 4 + r;
                obuf[(long long)q * LDAP + h * HDIM + dd] = f2bf(acc[qf][d][r] / L[r]);
            }
        }
    }
}

// ---------------- pipelined bf16 MFMA GEMM, 128x128x32, 3-buffer counted vmcnt ----
template<int EPI, bool GATHER, int CAUSAL>
__global__ __launch_bounds__(256) void gemm2_k(
    const unsigned short* __restrict__ A_, int lda, long long zsA,
    const unsigned short* __restrict__ B_, int ldb, long long zsB,
    void* __restrict__ C_, int ldc, long long zsC,
    const float* __restrict__ bias_, long long zsBias,
    const int* __restrict__ perm_, const int* __restrict__ pcnt,
    int N, int Kp,
    unsigned short* __restrict__ q_, unsigned short* __restrict__ k_,
    unsigned short* __restrict__ vt_) {
    const int z = blockIdx.z;
    const int gm0 = blockIdx.y * 128;
    const int n0 = blockIdx.x * 128;
    if (pcnt && gm0 >= pcnt[z]) return;
    if (CAUSAL == 1 && n0 >= gm0 + 128) return;

    const unsigned short* A = A_ + (long long)z * zsA;
    const unsigned short* B = B_ + (long long)z * zsB;
    const float* bias = bias_ ? bias_ + (long long)z * zsBias : nullptr;
    const int* perm = perm_ ? perm_ + (long long)z * 1024 : nullptr;

    __shared__ unsigned short Al[3][128 * 32];
    __shared__ unsigned short Bl[3][128 * 32];

    const int tid = threadIdx.x, lane = tid & 63, wid = tid >> 6;
    const int wr = wid >> 1, wc = wid & 1;
    const int c0 = wid * 2;
    const int lrow = lane >> 2;
    const int lseg = (lane & 3) * 8;

    const unsigned short* gA[2];
    const unsigned short* gB[2];
    #pragma unroll
    for (int i = 0; i < 2; ++i) {
        const int row = (c0 + i) * 16 + lrow;
        int ar = gm0 + row;
        if (GATHER) { const int p = perm[ar]; ar = (p < 0) ? 0 : p; }
        gA[i] = A + (long long)ar * lda + lseg;
        gB[i] = B + (long long)(n0 + row) * ldb + lseg;
    }

    int nt = Kp >> 5;
    if (CAUSAL == 2) { int ke = gm0 + 128; if (ke > Kp) ke = Kp; nt = ke >> 5; }

    f32x4 acc[4][4] = {};

    {
        const int t1 = (nt > 1) ? 1 : 0;
        #pragma unroll
        for (int i = 0; i < 2; ++i) {
            g2l16(gA[i], &Al[0][(c0 + i) * 512]);
            g2l16(gB[i], &Bl[0][(c0 + i) * 512]);
        }
        #pragma unroll
        for (int i = 0; i < 2; ++i) {
            g2l16(gA[i] + t1 * 32, &Al[1][(c0 + i) * 512]);
            g2l16(gB[i] + t1 * 32, &Bl[1][(c0 + i) * 512]);
        }
    }

    for (int t = 0; t < nt; ++t) {
        asm volatile("s_waitcnt vmcnt(4)" ::: "memory");
        __builtin_amdgcn_s_barrier();
        __builtin_amdgcn_sched_barrier(0);
        {
            const int ts = (t + 2 < nt) ? t + 2 : nt - 1;
            const int ko = ts * 32;
            const int bi = (t + 2) % 3;
            #pragma unroll
            for (int i = 0; i < 2; ++i) {
                g2l16(gA[i] + ko, &Al[bi][(c0 + i) * 512]);
                g2l16(gB[i] + ko, &Bl[bi][(c0 + i) * 512]);
            }
        }
        const int cur = t % 3;
        const int l15 = lane & 15, kfr = (lane >> 4) * 8;
        short8 af[4], bfv[4];
        #pragma unroll
        for (int m = 0; m < 4; ++m)
            af[m] = *(const short8*)&Al[cur][(wr * 64 + m * 16 + l15) * 32 + kfr];
        #pragma unroll
        for (int n = 0; n < 4; ++n)
            bfv[n] = *(const short8*)&Bl[cur][(wc * 64 + n * 16 + l15) * 32 + kfr];
        #pragma unroll
        for (int m = 0; m < 4; ++m)
            #pragma unroll
            for (int n = 0; n < 4; ++n)
                acc[m][n] = __builtin_amdgcn_mfma_f32_16x16x32_bf16(af[m], bfv[n], acc[m][n], 0, 0, 0);
    }

    // DRAIN: no LDS-DMA may be in flight at s_endpgm (round-3 race)
    asm volatile("s_waitcnt vmcnt(0) lgkmcnt(0)" ::: "memory");

    const int l15 = lane & 15, lq = (lane >> 4) * 4;
    #pragma unroll
    for (int m = 0; m < 4; ++m) {
        const int trow = wr * 64 + m * 16 + lq;
        #pragma unroll
        for (int n = 0; n < 4; ++n) {
            const int col = n0 + wc * 64 + n * 16 + l15;
            if (col >= N) continue;
            const float bv = bias ? bias[col] : 0.f;
            if (EPI == 5) {
                const int role = col / 1352;
                const int within = col - role * 1352;
                const int hh = within / 169;
                const int dd = within - hh * 169;
                if (role == 2) {
                    us4 pk;
                    #pragma unroll
                    for (int r = 0; r < 4; ++r) pk[r] = f2bf(acc[m][n][r] + bv);
                    *(us4*)&vt_[(long long)(hh * 256 + dd) * 1024 + gm0 + trow] = pk;
                } else {
                    unsigned short* dstb = role ? k_ : q_;
                    #pragma unroll
                    for (int r = 0; r < 4; ++r)
                        dstb[(long long)(gm0 + trow + r) * QS + hh * HP + dd] =
                            f2bf(acc[m][n][r] + bv);
                }
            } else {
                #pragma unroll
                for (int r = 0; r < 4; ++r) {
                    const int grow = gm0 + trow + r;
                    const float v = acc[m][n][r] + bv;
                    if (EPI == 0) {
                        ((float*)C_)[(long long)z * zsC + (long long)grow * ldc + col] = v;
                    } else if (EPI == 1) {
                        const int tok = perm[grow];
                        ((unsigned short*)C_)[(long long)z * zsC + (long long)grow * ldc + col] =
                            (tok >= 0) ? f2bf(fmaxf(v, 0.f)) : (unsigned short)0;
                    } else if (EPI == 2) {
                        ((float*)C_)[(long long)grow * ldc + col] += v;
                    } else if (EPI == 3) {
                        const int tok = perm[grow];
                        if (tok >= 0) ((float*)C_)[(long long)tok * ldc + col] += v;
                    }
                }
            }
        }
    }
}

extern "C" void kernel_launch(void* const* d_in, const int* in_sizes, int n_in,
                              void* d_out, int out_size, void* d_ws, size_t ws_size,
                              hipStream_t stream) {
    const float* x     = (const float*)d_in[0];
    const float* ln1_g = (const float*)d_in[1];
    const float* ln1_b = (const float*)d_in[2];
    const float* wqkv  = (const float*)d_in[3];
    const float* bqkv  = (const float*)d_in[4];
    const float* wo    = (const float*)d_in[5];
    const float* bo    = (const float*)d_in[6];
    const float* ln2_g = (const float*)d_in[7];
    const float* ln2_b = (const float*)d_in[8];
    const float* w1    = (const float*)d_in[9];
    const float* b1    = (const float*)d_in[10];
    const float* w2    = (const float*)d_in[11];
    const float* b2    = (const float*)d_in[12];

    float* h = (float*)d_out;

    char* w = (char*)d_ws;
    auto alloc = [&](size_t bytes) { void* p = w; w += (bytes + 255) & ~255ull; return p; };
    unsigned short* lnA   = (unsigned short*)alloc((size_t)S_LEN * LDAP * 2);
    unsigned short* qb    = (unsigned short*)alloc((size_t)S_LEN * QS * 2);
    unsigned short* kb    = (unsigned short*)alloc((size_t)S_LEN * QS * 2);
    unsigned short* VT    = (unsigned short*)alloc((size_t)NHEAD * 256 * 1024 * 2);
    unsigned short* obufb = (unsigned short*)alloc((size_t)S_LEN * LDAP * 2);
    unsigned short* hid   = (unsigned short*)alloc((size_t)4096 * KP2 * 2);
    unsigned short* wqkvT = (unsigned short*)alloc((size_t)4096 * LDAP * 2);      // 11.3 MB
    unsigned short* woT   = (unsigned short*)alloc((size_t)1408 * LDAP * 2);      // 3.87 MB
    char*           U     = (char*)alloc((size_t)62000000);                       // union: w1T/w2T (L3-hot)
    int* perm = (int*)alloc(4096 * 4);
    int* pcnt = (int*)alloc(64);

    unsigned short* w1T = (unsigned short*)U;                               // 31.0 MB
    unsigned short* w2T = (unsigned short*)(U + (size_t)4 * 2816 * LDAP * 2); // 30.6 MB

    hipMemcpyAsync(h, x, (size_t)S_LEN * DMODEL * 4, hipMemcpyDeviceToDevice, stream);
    // q/k head-pad slots enter the QK^T MFMA -> must be zero
    hipMemsetAsync(qb, 0, (size_t)S_LEN * QS * 2, stream);
    hipMemsetAsync(kb, 0, (size_t)S_LEN * QS * 2, stream);
    route_k<<<1, 256, 0, stream>>>(x, perm, pcnt);

    const float scale = 1.0f / 13.0f;

    for (int l = 0; l < NLAYER; ++l) {
        const float* wqkv_l = wqkv + (long long)l * DMODEL * TD;
        const float* wo_l   = wo   + (long long)l * DMODEL * DMODEL;
        const float* w1_l   = w1   + (long long)l * 4 * DMODEL * DFFN;
        const float* w2_l   = w2   + (long long)l * 4 * DFFN * DMODEL;

        // per-layer weight conversion: dst stays L3-resident for the gemm that follows
        tconv_k<<<dim3(43, 127, 1), 256, 0, stream>>>(wqkv_l, wqkvT, DMODEL, TD, LDAP, 0, 0);
        tconv_k<<<dim3(43, 43, 1), 256, 0, stream>>>(wo_l, woT, DMODEL, DMODEL, LDAP, 0, 0);

        ln_k<<<1024, 256, 0, stream>>>(h, ln1_g + l * DMODEL, ln1_b + l * DMODEL, lnA, DMODEL, LDAP);
        // QKV -> split bf16 q/k (head-padded) + V transposed
        gemm2_k<5, false, 0><<<dim3(32, 8, 1), 256, 0, stream>>>(
            lnA, LDAP, 0, wqkvT, LDAP, 0, nullptr, 0, 0,
            bqkv + l * TD, 0, nullptr, nullptr, TD, LDAP, qb, kb, VT);
        // fused flash attention -> obufb [1024][1376] (compact cols, bf16)
        flash_k<<<dim3(8, 8), 256, 0, stream>>>(qb, kb, VT, obufb, scale);
        // h += o @ wo + bo
        gemm2_k<2, false, 0><<<dim3(11, 8, 1), 256, 0, stream>>>(
            obufb, LDAP, 0, woT, LDAP, 0, h, DMODEL, 0,
            bo + l * DMODEL, 0, nullptr, nullptr, DMODEL, LDAP, nullptr, nullptr, nullptr);

        tconv_k<<<dim3(43, 85, 4), 256, 0, stream>>>(
            w1_l, w1T, DMODEL, DFFN, LDAP, (long long)DMODEL * DFFN, (long long)2816 * LDAP);
        tconv_k<<<dim3(85, 43, 4), 256, 0, stream>>>(
            w2_l, w2T, DFFN, DMODEL, KP2, (long long)DFFN * DMODEL, (long long)1408 * KP2);

        ln_k<<<1024, 256, 0, stream>>>(h, ln2_g + l * DMODEL, ln2_b + l * DMODEL, lnA, DMODEL, LDAP);
        gemm2_k<1, true, 0><<<dim3(22, 8, 4), 256, 0, stream>>>(
            lnA, LDAP, 0, w1T, LDAP, (long long)2816 * LDAP,
            hid, KP2, (long long)1024 * KP2,
            b1 + (long long)l * 4 * DFFN, DFFN, perm, pcnt, DFFN, LDAP,
            nullptr, nullptr, nullptr);
        gemm2_k<3, false, 0><<<dim3(11, 8, 4), 256, 0, stream>>>(
            hid, KP2, (long long)1024 * KP2, w2T, KP2, (long long)1408 * KP2,
            h, DMODEL, 0,
            b2 + (long long)l * 4 * DMODEL, DMODEL, perm, pcnt, DMODEL, KP2,
            nullptr, nullptr, nullptr);
    }
}